// Round 11
// baseline (17.187 us; speedup 1.0000x reference)
//
#include <hip/hip_runtime.h>

#define NH 64
#define LFULL 2048
#define MH 1024
#define PI_F 3.14159265358979323846f
#define ANG_HALF 1.5339807878856412e-3f   // pi/2048
#define ANG_3A   3.0679615757712823e-3f   // pi/1024

typedef __attribute__((ext_vector_type(2))) float f32x2;
typedef __attribute__((ext_vector_type(4))) float f32x4;

#define SV2(v, i, j) __builtin_shufflevector((v), (v), (i), (j))
// acc += pair.lo * uv   (coefficient broadcast from LOW half via op_sel)
#define PK_FMA_LO(acc, pair, uv) \
    asm("v_pk_fma_f32 %0, %1, %2, %0 op_sel:[0,0,0] op_sel_hi:[0,1,1]" \
        : "+v"(acc) : "v"(pair), "v"(uv))
// acc += pair.hi * uv   (broadcast HIGH half)
#define PK_FMA_HI(acc, pair, uv) \
    asm("v_pk_fma_f32 %0, %1, %2, %0 op_sel:[1,0,0] op_sel_hi:[1,1,1]" \
        : "+v"(acc) : "v"(pair), "v"(uv))

__global__ __launch_bounds__(512) void hippo_ssk(
    const float* __restrict__ w_ri,
    const float* __restrict__ P_ri,
    const float* __restrict__ B_ri,
    const float* __restrict__ C_ri,
    const float* __restrict__ log_dt,
    float* __restrict__ out)
{
    // Unduplicated coefficients, 48B row (16B-aligned):
    // [na2, m2, P1_00, P0_00 | P1_01, P0_01, P1_10, P0_10 | P1_11, P0_11, pad, pad]
    __shared__ __attribute__((aligned(16))) float pole2[NH][12];
    __shared__ float2 Kf[MH + 1];
    __shared__ float2 bufA[MH];
    __shared__ float2 bufB[MH];

    const int h    = blockIdx.x;
    const int tid  = threadIdx.x;
    const int lane = tid & 63;

    // ---------------- Stage 1: per-pole coefficients — ALL waves, redundant ----------------
    // Each wave's 64 lanes cover all 64 poles; identical values -> benign LDS race;
    // same-wave write->read ordering makes the stage1->stage2 barrier unnecessary.
    {
        const float dt = __expf(log_dt[h]);
        const float2 w = ((const float2*)w_ri)[h*NH + lane];
        const float2 P = ((const float2*)P_ri)[h*NH + lane];
        const float2 B = ((const float2*)B_ri)[h*NH + lane];
        const float2 C = ((const float2*)C_ri)[h*NH + lane];
        const float a = w.x * dt, b = w.y * dt;
        const float v00r = (B.x*C.x - B.y*C.y) * dt;
        const float v00i = (B.x*C.y + B.y*C.x) * dt;
        const float v01r = (B.x*P.x + B.y*P.y) * dt;   // B*conj(P)
        const float v01i = (B.y*P.x - B.x*P.y) * dt;
        const float v10r = (P.x*C.x - P.y*C.y) * dt;   // P*C
        const float v10i = (P.x*C.y + P.y*C.x) * dt;
        const float v11  = (P.x*P.x + P.y*P.y) * dt;   // |P|^2 (real)
        float4* pp = (float4*)pole2[lane];
        pp[0] = make_float4(-2.f*a, fmaf(a, a, b*b),
                            -2.f*fmaf(v00r, a, v00i*b), 2.f*v00r);
        pp[1] = make_float4(-2.f*fmaf(v01r, a, v01i*b), 2.f*v01r,
                            -2.f*fmaf(v10r, a, v10i*b), 2.f*v10r);
        *(float2*)&pole2[lane][8] = make_float2(-2.f*v11*a, 2.f*v11);
        // Nyquist bin (z->inf limit): Re(sum v00); every wave reduces, wave 0 writes.
        float s = v00r;
        #pragma unroll
        for (int off = 32; off > 0; off >>= 1) s += __shfl_down(s, off, 64);
        if (tid == 0) Kf[MH] = make_float2(s, 0.f);
    }
    // NO barrier: each wave reads only rows it wrote itself.

    // ---------------- Stage 2: Cauchy kernel, freqs (tid, tid+512) packed ----------------
    // pair(v) at z=iy: [P1 + i*P0*y]/[(m2-y^2) + i*na2*y]
    // accumulate s1=ΣP1U, s2=ΣP1V, s3=ΣP0U, s4=ΣP0V; r = (s1+y*s4, y*s3-s2)
    {
        const int lA = tid;
        const int lB = tid + 512;
        float shA, chA, shB, chB;
        __sincosf(ANG_HALF * (float)lA, &shA, &chA);
        __sincosf(ANG_HALF * (float)lB, &shB, &chB);
        const float yA = 2.f * shA * __builtin_amdgcn_rcpf(chA);
        const float yB = 2.f * shB * __builtin_amdgcn_rcpf(chB);
        f32x2 yp;  yp.x = yA;       yp.y = yB;
        f32x2 ny2; ny2.x = -yA*yA;  ny2.y = -yB*yB;
        f32x2 s1_00={0,0}, s2_00={0,0}, s3_00={0,0}, s4_00={0,0};
        f32x2 s1_01={0,0}, s2_01={0,0}, s3_01={0,0}, s4_01={0,0};
        f32x2 s1_10={0,0}, s2_10={0,0}, s3_10={0,0}, s4_10={0,0};
        f32x2 s1_11={0,0}, s2_11={0,0}, s3_11={0,0}, s4_11={0,0};
        #pragma unroll 4
        for (int n = 0; n < NH; ++n) {
            const f32x4 q0 = *reinterpret_cast<const f32x4*>(&pole2[n][0]);
            const f32x4 q1 = *reinterpret_cast<const f32x4*>(&pole2[n][4]);
            const f32x2 q2 = *reinterpret_cast<const f32x2*>(&pole2[n][8]);
            const f32x2 nm  = SV2(q0, 0, 1);   // (na2, m2)
            const f32x2 p00 = SV2(q0, 2, 3);   // (P1_00, P0_00)
            const f32x2 p01 = SV2(q1, 0, 1);
            const f32x2 p10 = SV2(q1, 2, 3);
            f32x2 dr, di;
            // dr = m2 + ny2 (broadcast hi of nm); di = na2 * yp (broadcast lo)
            asm("v_pk_add_f32 %0, %1, %2 op_sel:[1,0] op_sel_hi:[1,1]"
                : "=v"(dr) : "v"(nm), "v"(ny2));
            asm("v_pk_mul_f32 %0, %1, %2 op_sel:[0,0] op_sel_hi:[0,1]"
                : "=v"(di) : "v"(nm), "v"(yp));
            const f32x2 den = dr*dr + di*di;
            // batched reciprocal: one rcp for both freqs
            const float pp  = den.x * den.y;
            const float ipp = __builtin_amdgcn_rcpf(pp);
            f32x2 t;  t.x = ipp * den.y;  t.y = ipp * den.x;
            const f32x2 U = dr * t;
            const f32x2 V = di * t;
            PK_FMA_LO(s1_00, p00, U);  PK_FMA_LO(s2_00, p00, V);
            PK_FMA_HI(s3_00, p00, U);  PK_FMA_HI(s4_00, p00, V);
            PK_FMA_LO(s1_01, p01, U);  PK_FMA_LO(s2_01, p01, V);
            PK_FMA_HI(s3_01, p01, U);  PK_FMA_HI(s4_01, p01, V);
            PK_FMA_LO(s1_10, p10, U);  PK_FMA_LO(s2_10, p10, V);
            PK_FMA_HI(s3_10, p10, U);  PK_FMA_HI(s4_10, p10, V);
            PK_FMA_LO(s1_11, q2,  U);  PK_FMA_LO(s2_11, q2,  V);
            PK_FMA_HI(s3_11, q2,  U);  PK_FMA_HI(s4_11, q2,  V);
        }
        // Combine: r = (s1 + y*s4, y*s3 - s2)
        const f32x2 r00r = yp*s4_00 + s1_00;
        const f32x2 r00i = yp*s3_00 - s2_00;
        const f32x2 r01r = yp*s4_01 + s1_01;
        const f32x2 r01i = yp*s3_01 - s2_01;
        const f32x2 r10r = yp*s4_10 + s1_10;
        const f32x2 r10i = yp*s3_10 - s2_10;
        const f32x2 r11r = yp*s4_11 + s1_11;
        const f32x2 r11i = yp*s3_11 - s2_11;
        // Woodbury: k0 = r00 - r01*r10/(1+r11)
        const f32x2 nr = r01r*r10r - r01i*r10i;
        const f32x2 ni = r01r*r10i + r01i*r10r;
        const f32x2 dw = 1.f + r11r;
        const f32x2 dv = r11i;
        const f32x2 d2 = dw*dw + dv*dv;
        f32x2 id2;
        id2.x = __builtin_amdgcn_rcpf(d2.x);
        id2.y = __builtin_amdgcn_rcpf(d2.y);
        const f32x2 cr = (nr*dw + ni*dv)*id2;
        const f32x2 ci = (ni*dw - nr*dv)*id2;
        const f32x2 k0r = r00r - cr;
        const f32x2 k0i = r00i - ci;
        const f32x2 hy = 0.5f*yp;               // * 2/(1+omega) = 1 + i*y/2
        Kf[lA] = make_float2(k0r.x - k0i.x*hy.x, k0i.x + k0r.x*hy.x);
        Kf[lB] = make_float2(k0r.y - k0i.y*hy.y, k0i.y + k0r.y*hy.y);
    }
    __syncthreads();

    // ---------------- Stage 3: fused 3a + FFT stage 0 (in-register) ----------------
    // 3a: Z[k] = E + i*O from half-spectrum; stage-0 butterfly pairs (tid, tid+512).
    float2 wtw;   // running Stockham twiddle e^{+i*pi*jm/512}
    {
        float sa, ca;
        __sincosf(ANG_3A * (float)tid, &sa, &ca);
        // k0 = tid
        float2 Xk = Kf[tid];
        if (tid == 0) Xk.y = 0.f;
        float2 Xc = Kf[MH - tid];  Xc.y = -Xc.y;
        const float Er0 = 0.5f*(Xk.x + Xc.x), Ei0 = 0.5f*(Xk.y + Xc.y);
        const float Tr0 = 0.5f*(Xk.x - Xc.x), Ti0 = 0.5f*(Xk.y - Xc.y);
        const float Or0 = ca*Tr0 - sa*Ti0;
        const float Oi0 = ca*Ti0 + sa*Tr0;
        const float2 Z0 = make_float2(Er0 - Oi0, Ei0 + Or0);
        // k1 = tid + 512; twiddle = i*(ca,sa) = (-sa, ca)
        const float2 Xk1 = Kf[tid + 512];
        float2 Xc1 = Kf[512 - tid];  Xc1.y = -Xc1.y;
        const float Er1 = 0.5f*(Xk1.x + Xc1.x), Ei1 = 0.5f*(Xk1.y + Xc1.y);
        const float Tr1 = 0.5f*(Xk1.x - Xc1.x), Ti1 = 0.5f*(Xk1.y - Xc1.y);
        const float Or1 = -sa*Tr1 - ca*Ti1;
        const float Oi1 = -sa*Ti1 + ca*Tr1;
        const float2 Z1 = make_float2(Er1 - Oi1, Ei1 + Or1);
        // stage-0 butterfly: twiddle w0 = (ca+i*sa)^2 = e^{+i*pi*tid/512}
        const float cw = ca*ca - sa*sa;
        const float sw = 2.f*ca*sa;
        bufA[2*tid]     = make_float2(Z0.x + Z1.x, Z0.y + Z1.y);
        const float drr = Z0.x - Z1.x, dii = Z0.y - Z1.y;
        bufA[2*tid + 1] = make_float2(cw*drr - sw*dii, cw*dii + sw*drr);
        wtw = make_float2(cw, sw);
        // recurrence update for stage m=2: if (tid&1) w *= e^{-i*pi/512}
        const float mc = (tid & 1) ? 0.99998118f : 1.f;
        const float ms = (tid & 1) ? 0.00613588f : 0.f;
        wtw = make_float2(wtw.x*mc + wtw.y*ms, wtw.y*mc - wtw.x*ms);
    }
    __syncthreads();

    // ---------------- FFT stages m = 2 .. 256 (8 stages, LDS ping-pong) ----------------
    {
        // e^{-i*pi*m/512} per stage (cos, sin)
        const float CM_C[7] = {0.99992470f, 0.99969882f, 0.99879546f, 0.99518473f,
                               0.98078528f, 0.92387953f, 0.70710678f};
        const float CM_S[7] = {0.01227154f, 0.02454123f, 0.04906767f, 0.09801714f,
                               0.19509032f, 0.38268343f, 0.70710678f};
        float2* Xb = bufA;
        float2* Yb = bufB;
        int m = 2;
        #pragma unroll
        for (int st = 0; st < 8; ++st) {
            const int jm = tid & ~(m - 1);
            const float2 c0 = Xb[tid];
            const float2 c1 = Xb[tid + 512];
            const int o0 = tid + jm;
            const float drr = c0.x - c1.x, dii = c0.y - c1.y;
            Yb[o0]     = make_float2(c0.x + c1.x, c0.y + c1.y);
            Yb[o0 + m] = make_float2(wtw.x*drr - wtw.y*dii, wtw.x*dii + wtw.y*drr);
            if (st < 7) {   // prepare next stage's twiddle
                const float mc = (tid & m) ? CM_C[st] : 1.f;
                const float ms = (tid & m) ? CM_S[st] : 0.f;
                wtw = make_float2(wtw.x*mc + wtw.y*ms, wtw.y*mc - wtw.x*ms);
            }
            __syncthreads();
            float2* t = Xb; Xb = Yb; Yb = t;
            m <<= 1;
        }
        // ---------------- Final stage m=512 (twiddle-free) fused with store ----------------
        const float sc = 1.0f/1024.0f;
        float2* op2 = (float2*)(out + (size_t)h * LFULL);
        const float2 c0 = Xb[tid];
        const float2 c1 = Xb[tid + 512];
        op2[tid]       = make_float2((c0.x + c1.x)*sc, (c0.y + c1.y)*sc);
        op2[tid + 512] = make_float2((c0.x - c1.x)*sc, (c0.y - c1.y)*sc);
    }
}

extern "C" void kernel_launch(void* const* d_in, const int* in_sizes, int n_in,
                              void* d_out, int out_size, void* d_ws, size_t ws_size,
                              hipStream_t stream) {
    const float* w_ri   = (const float*)d_in[0];
    const float* P_ri   = (const float*)d_in[1];
    const float* B_ri   = (const float*)d_in[2];
    const float* C_ri   = (const float*)d_in[3];
    const float* log_dt = (const float*)d_in[4];
    float* out = (float*)d_out;
    const int Hn = in_sizes[4];   // 256 heads
    hippo_ssk<<<dim3(Hn), dim3(512), 0, stream>>>(w_ri, P_ri, B_ri, C_ri, log_dt, out);
}